// Round 14
// baseline (60.823 us; speedup 1.0000x reference)
//
#include <hip/hip_runtime.h>
#include <hip/hip_fp16.h>

// BallQLoss: B=2, N=8192, K=16, radius=0.5, L1 norm, mean over (B,N,K).
// v8b: byte-identical resubmit of v8 (container flapped pre-push again).
// K1 scan: 1024 blocks = 256 query-groups x 4 j-slices; block = 64 queries
// x 2048 candidates (1024 f16x2 pairs staged in LDS planes, ~30 KB -> 4
// blocks/CU = 8 waves/SIMD = max occupancy). Wave c scans 128 pairs in 2
// rounds; packed v_pk f16 distance with -R^2 folded into the fma chain
// (9 VALU/pair); hit = sign bit merged into four independent mask chains;
// extraction in ascending j (pointnet2 first-K semantics). Per-slice
// first-16 lists (u16) + count bytes -> d_ws. Block 0 resets accum/done
// (stream order: scan completes before any loss block runs).
// K2 loss: 16 lanes/query, slice-decode, padded slots -> first neighbor;
// flow gather + L1; block partial -> atomicAdd(accum); last finisher
// (done counter) writes the mean to d_out. Replay-safe throughout.

#define NQ   8192
#define NB   2
#define KNN  16
#define QPB  64
#define WAVES 8
#define THREADS (QPB * WAVES)          // 512
#define NBQ (NB * NQ)                  // 16384
#define GROUPS (NBQ / QPB)             // 256
#define SLICES 4
#define SL_PAIRS 1024                  // pairs per slice (2048 candidates)
#define WPP 128                        // pairs per wave (2 rounds of 64)
#define IDXROW 130                     // u16/row: 8 lists * 16 + 2 pad

static __device__ __forceinline__ unsigned pkrtz_u(float a, float b) {
    return __builtin_bit_cast(unsigned, __builtin_amdgcn_cvt_pkrtz(a, b));
}
static __device__ __forceinline__ __half2 u_as_h2(unsigned u) {
    return __builtin_bit_cast(__half2, u);
}
// one candidate PAIR: packed f16 (d2 - R^2) via fused fma chain; sign bits
// (bit15 = even cand, bit31 = odd cand) merged into mask chain mm.
static __device__ __forceinline__ void bq_pair(unsigned xu, unsigned yu,
                                               unsigned zu, __half2 qpx,
                                               __half2 qpy, __half2 qpz,
                                               __half2 nr2, unsigned& mm) {
    const __half2 dx = __hsub2(qpx, u_as_h2(xu));
    const __half2 dy = __hsub2(qpy, u_as_h2(yu));
    const __half2 dz = __hsub2(qpz, u_as_h2(zu));
    const __half2 t =
        __hfma2(dx, dx, __hfma2(dy, dy, __hfma2(dz, dz, nr2)));
    const unsigned su = __builtin_bit_cast(unsigned, t) & 0x80008000u;
    mm = su | (mm >> 1);
}

__global__ __launch_bounds__(THREADS, 8)
void ballq_scan(const float* __restrict__ pc,
                unsigned short* __restrict__ wsIdx,
                unsigned char* __restrict__ wsCnt,
                float* __restrict__ accum,
                unsigned* __restrict__ done)
{
    __shared__ __align__(16) unsigned lx[SL_PAIRS];   // 4 KB each
    __shared__ __align__(16) unsigned ly[SL_PAIRS];
    __shared__ __align__(16) unsigned lz[SL_PAIRS];
    __shared__ unsigned short s_idx[QPB][IDXROW];     // 16.6 KB
    __shared__ unsigned char  s_cnt[QPB][12];

    const int tid = threadIdx.x;
    const int q   = tid & 63;          // lane = query slot
    const int c   = tid >> 6;          // wave id
    const int s   = blockIdx.x & 3;    // j slice
    const int g   = blockIdx.x >> 2;   // query group 0..255
    const int b   = g >> 7;
    const int i   = (g & 127) * QPB + q;

    if (blockIdx.x == 0 && tid == 0) { *accum = 0.0f; *done = 0u; }

    const float* __restrict__ pcb = pc + (size_t)b * NQ * 3;
    const float2* __restrict__ f2 = (const float2*)pcb;

    // ---- stage this slice's 1024 pairs into LDS planes (f16x2) ----
    for (int p = tid; p < SL_PAIRS; p += THREADS) {
        const int gp = s * SL_PAIRS + p;
        const float2 v0 = f2[3 * gp + 0];   // (x_e, y_e)
        const float2 v1 = f2[3 * gp + 1];   // (z_e, x_o)
        const float2 v2 = f2[3 * gp + 2];   // (y_o, z_o)
        lx[p] = pkrtz_u(v0.x, v1.y);
        ly[p] = pkrtz_u(v0.y, v2.x);
        lz[p] = pkrtz_u(v1.x, v2.y);
    }

    const float qx = pcb[i * 3 + 0];
    const float qy = pcb[i * 3 + 1];
    const float qz = pcb[i * 3 + 2];
    const __half2 qpx = u_as_h2(pkrtz_u(qx, qx));
    const __half2 qpy = u_as_h2(pkrtz_u(qy, qy));
    const __half2 qpz = u_as_h2(pkrtz_u(qz, qz));
    const __half2 nr2 = u_as_h2(0xB400B400u);   // (-0.25, -0.25)

    __syncthreads();

    // ---- scan: wave c owns pairs [c*WPP, c*WPP+WPP), 2 rounds of 64 ----
    int cnt = 0;
    for (int r = 0; r < WPP / 64 && cnt < KNN; ++r) {
        const int pbase = c * WPP + r * 64;
        unsigned m[4] = {0u, 0u, 0u, 0u};
#pragma unroll
        for (int g4 = 0; g4 < 4; ++g4) {
#pragma unroll
            for (int w = 0; w < 4; ++w) {
                const int pb = pbase + w * 16 + g4 * 4;
                const uint4 X = *(const uint4*)&lx[pb];  // broadcast b128
                const uint4 Y = *(const uint4*)&ly[pb];
                const uint4 Z = *(const uint4*)&lz[pb];
                bq_pair(X.x, Y.x, Z.x, qpx, qpy, qpz, nr2, m[w]);
                bq_pair(X.y, Y.y, Z.y, qpx, qpy, qpz, nr2, m[w]);
                bq_pair(X.z, Y.z, Z.z, qpx, qpy, qpz, nr2, m[w]);
                bq_pair(X.w, Y.w, Z.w, qpx, qpy, qpz, nr2, m[w]);
            }
        }
        // bit n of ev/od = pair (pbase+n) even/odd candidate
        unsigned long long ev =
              (unsigned long long)(m[0] & 0xFFFFu)
            | ((unsigned long long)(m[1] & 0xFFFFu) << 16)
            | ((unsigned long long)(m[2] & 0xFFFFu) << 32)
            | ((unsigned long long)(m[3] & 0xFFFFu) << 48);
        unsigned long long od =
              (unsigned long long)(m[0] >> 16)
            | ((unsigned long long)(m[1] >> 16) << 16)
            | ((unsigned long long)(m[2] >> 16) << 32)
            | ((unsigned long long)(m[3] >> 16) << 48);

        const int jb = s * (2 * SL_PAIRS) + 2 * pbase;
        while ((ev | od) && cnt < KNN) {
            const int pe = ev ? __builtin_ctzll(ev) : 127;
            const int po = od ? __builtin_ctzll(od) : 127;
            int j;
            if (pe <= po) { j = jb + 2 * pe;     ev &= ev - 1; }
            else          { j = jb + 2 * po + 1; od &= od - 1; }
            s_idx[q][c * KNN + cnt] = (unsigned short)j;
            ++cnt;
        }
    }
    s_cnt[q][c] = (unsigned char)cnt;
    __syncthreads();

    // ---- merge (wave 0, lane = query): first <=16 over this slice ----
    if (c == 0) {
        const int qid = g * QPB + q;   // 0..16383
        unsigned short* __restrict__ rp =
            wsIdx + ((size_t)s * NBQ + qid) * KNN;
        int outc = 0;
        for (int c2 = 0; c2 < WAVES && outc < KNN; ++c2) {
            const int f = s_cnt[q][c2];
            const int take = f < (KNN - outc) ? f : (KNN - outc);
            for (int t = 0; t < take; ++t)
                rp[outc++] = s_idx[q][c2 * KNN + t];
        }
        wsCnt[qid * 4 + s] = (unsigned char)outc;
    }
}

__global__ __launch_bounds__(256)
void ballq_loss(const float* __restrict__ flow,
                const unsigned short* __restrict__ wsIdx,
                const unsigned char* __restrict__ wsCnt,
                float* __restrict__ accum,
                unsigned* __restrict__ done,
                float* __restrict__ out,
                int nblocks)
{
    const int tid = blockIdx.x * 256 + threadIdx.x;
    const int qid = tid >> 4;          // one query per 16 lanes
    const int t   = tid & 15;          // k-slot
    const int b   = qid >> 13;
    const int iq  = qid & (NQ - 1);
    const float* __restrict__ flb = flow + (size_t)b * NQ * 3;

    const unsigned cw = *(const unsigned*)(wsCnt + qid * 4);
    const int b0 = cw & 0xFF;
    const int b1 = (cw >> 8)  & 0xFF;
    const int b2 = (cw >> 16) & 0xFF;
    const int c1 = b0, c2c = b0 + b1, c3 = b0 + b1 + b2;
    int tot = c3 + ((cw >> 24) & 0xFF);
    if (tot > KNN) tot = KNN;
    // tot >= 1 always: self is in-ball (exact f16 zero distance)

    const int seff = (t < tot) ? t : 0;   // padded slots -> first neighbor
    const int sl   = (seff >= c1) + (seff >= c2c) + (seff >= c3);
    const int cum  = (sl == 0) ? 0 : (sl == 1) ? c1 : (sl == 2) ? c2c : c3;
    const int j    = wsIdx[((size_t)sl * NBQ + qid) * KNN + (seff - cum)];

    const float fx = flb[iq * 3 + 0];
    const float fy = flb[iq * 3 + 1];
    const float fz = flb[iq * 3 + 2];
    float l = fabsf(fx - flb[j * 3 + 0]) +
              fabsf(fy - flb[j * 3 + 1]) +
              fabsf(fz - flb[j * 3 + 2]);

    for (int o = 32; o > 0; o >>= 1)
        l += __shfl_down(l, o, 64);
    __shared__ float sred[4];
    if ((threadIdx.x & 63) == 0) sred[threadIdx.x >> 6] = l;
    __syncthreads();
    if (threadIdx.x == 0) {
        atomicAdd(accum, sred[0] + sred[1] + sred[2] + sred[3]);
        __threadfence();
        if (atomicAdd(done, 1u) == (unsigned)(nblocks - 1)) {
            // all blocks' accum-adds happened-before their done-adds
            const float total = atomicAdd(accum, 0.0f);  // device-scope read
            out[0] = total * (1.0f / ((float)NB * NQ * KNN));
        }
    }
}

extern "C" void kernel_launch(void* const* d_in, const int* in_sizes, int n_in,
                              void* d_out, int out_size, void* d_ws, size_t ws_size,
                              hipStream_t stream)
{
    (void)in_sizes; (void)n_in; (void)out_size; (void)ws_size;
    const float* pc   = (const float*)d_in[0];
    const float* flow = (const float*)d_in[1];
    float* out = (float*)d_out;

    // ws layout: idx lists (4 slices x 16384 q x 16 u16 = 2 MB),
    //            counts (16384 x 4 B), accum + done header
    unsigned short* wsIdx = (unsigned short*)d_ws;
    unsigned char*  wsCnt = (unsigned char*)d_ws + (size_t)SLICES * NBQ * KNN * 2;
    float*    accum = (float*)(wsCnt + (size_t)NBQ * 4);
    unsigned* done  = (unsigned*)(accum + 1);

    const int nloss = NBQ * 16 / 256;   // 1024
    ballq_scan<<<GROUPS * SLICES, THREADS, 0, stream>>>(pc, wsIdx, wsCnt, accum, done);
    ballq_loss<<<nloss, 256, 0, stream>>>(flow, wsIdx, wsCnt, accum, done, out, nloss);
}

// Round 15
// 40.968 us; speedup vs baseline: 1.4846x; 1.4846x over previous
//
#include <hip/hip_runtime.h>
#include <hip/hip_fp16.h>

// BallQLoss: B=2, N=8192, K=16, radius=0.5, L1 norm, mean over (B,N,K).
// v9: v7 skeleton (3 kernels + tiny prep; NO single-address atomics — v8
// proved the last-finisher pattern costs ~25 us) with the scan's candidate
// reads moved OFF the LDS pipe onto the scalar path.
// K0 prep: pack pc into f16x2 planes in d_ws (96 KB).
// K1 scan: 1024 blocks = 256 query-groups x 4 j-slices, 8 waves. Wave c
// reads its 128 pairs via readfirstlane-uniform indices -> s_load/uniform
// loads (SGPR operands feed v_pk math directly); 9 VALU/pair; hit = sign
// bit of fma chain merged into 4 independent mask chains; extraction in
// ascending j (pointnet2 first-K semantics). Per-slice first-16 lists
// (u16) + count bytes -> d_ws. LDS only for s_idx/s_cnt (~17 KB).
// K2 loss: 16 lanes/query, slice-decode, padded slots -> first neighbor;
// flow gather + L1; per-block partial -> plain store.
// K3 final: 1 block reduces 1024 partials -> mean. Replay-safe throughout.

#define NQ   8192
#define NB   2
#define KNN  16
#define QPB  64
#define WAVES 8
#define THREADS (QPB * WAVES)          // 512
#define NBQ (NB * NQ)                  // 16384
#define GROUPS (NBQ / QPB)             // 256
#define SLICES 4
#define SL_PAIRS 1024                  // pairs per slice (2048 candidates)
#define WPP 128                        // pairs per wave (2 rounds of 64)
#define NPAIRS (NQ / 2)                // 4096 pairs per batch
#define IDXROW 130                     // u16/row: 8 lists * 16 + 2 pad

static __device__ __forceinline__ unsigned pkrtz_u(float a, float b) {
    return __builtin_bit_cast(unsigned, __builtin_amdgcn_cvt_pkrtz(a, b));
}
static __device__ __forceinline__ __half2 u_as_h2(unsigned u) {
    return __builtin_bit_cast(__half2, u);
}
// one candidate PAIR: packed f16 (d2 - R^2) via fused fma chain; sign bits
// (bit15 = even cand, bit31 = odd cand) merged into mask chain mm.
static __device__ __forceinline__ void bq_pair(unsigned xu, unsigned yu,
                                               unsigned zu, __half2 qpx,
                                               __half2 qpy, __half2 qpz,
                                               __half2 nr2, unsigned& mm) {
    const __half2 dx = __hsub2(qpx, u_as_h2(xu));
    const __half2 dy = __hsub2(qpy, u_as_h2(yu));
    const __half2 dz = __hsub2(qpz, u_as_h2(zu));
    const __half2 t =
        __hfma2(dx, dx, __hfma2(dy, dy, __hfma2(dz, dz, nr2)));
    const unsigned su = __builtin_bit_cast(unsigned, t) & 0x80008000u;
    mm = su | (mm >> 1);
}

// K0: pack both batches' pc into f16x2 coordinate planes.
// Layout: wsPk[(b*3 + coord) * NPAIRS + pair]
__global__ __launch_bounds__(256)
void ballq_prep(const float* __restrict__ pc, unsigned* __restrict__ wsPk)
{
    const int p  = blockIdx.x * 256 + threadIdx.x;   // 0..8191
    const int b  = p >> 12;
    const int pp = p & (NPAIRS - 1);
    const float2* __restrict__ f2 = (const float2*)(pc + (size_t)b * NQ * 3);
    const float2 v0 = f2[3 * pp + 0];   // (x_e, y_e)
    const float2 v1 = f2[3 * pp + 1];   // (z_e, x_o)
    const float2 v2 = f2[3 * pp + 2];   // (y_o, z_o)
    wsPk[(b * 3 + 0) * NPAIRS + pp] = pkrtz_u(v0.x, v1.y);
    wsPk[(b * 3 + 1) * NPAIRS + pp] = pkrtz_u(v0.y, v2.x);
    wsPk[(b * 3 + 2) * NPAIRS + pp] = pkrtz_u(v1.x, v2.y);
}

__global__ __launch_bounds__(THREADS, 8)
void ballq_scan(const float* __restrict__ pc,
                const unsigned* __restrict__ wsPk,
                unsigned short* __restrict__ wsIdx,
                unsigned char* __restrict__ wsCnt)
{
    __shared__ unsigned short s_idx[QPB][IDXROW];     // 16.6 KB
    __shared__ unsigned char  s_cnt[QPB][12];

    const int tid = threadIdx.x;
    const int q   = tid & 63;          // lane = query slot
    // wave id, forced uniform so candidate loads scalarize (s_load)
    const int cU  = __builtin_amdgcn_readfirstlane(tid >> 6);
    const int s   = blockIdx.x & 3;    // j slice (uniform)
    const int g   = blockIdx.x >> 2;   // query group 0..255 (uniform)
    const int b   = g >> 7;
    const int i   = (g & 127) * QPB + q;

    const float* __restrict__ pcb = pc + (size_t)b * NQ * 3;
    const float qx = pcb[i * 3 + 0];
    const float qy = pcb[i * 3 + 1];
    const float qz = pcb[i * 3 + 2];
    const __half2 qpx = u_as_h2(pkrtz_u(qx, qx));
    const __half2 qpy = u_as_h2(pkrtz_u(qy, qy));
    const __half2 qpz = u_as_h2(pkrtz_u(qz, qz));
    const __half2 nr2 = u_as_h2(0xB400B400u);   // (-0.25, -0.25)

    // uniform uint4 plane pointers for this batch
    const uint4* __restrict__ px4 = (const uint4*)(wsPk + (b * 3 + 0) * NPAIRS);
    const uint4* __restrict__ py4 = (const uint4*)(wsPk + (b * 3 + 1) * NPAIRS);
    const uint4* __restrict__ pz4 = (const uint4*)(wsPk + (b * 3 + 2) * NPAIRS);

    // ---- scan: wave cU owns pairs [s*1024 + cU*128, +128), 2 rounds ----
    int cnt = 0;
    for (int r = 0; r < WPP / 64 && cnt < KNN; ++r) {
        const int pbase = s * SL_PAIRS + cU * WPP + r * 64;  // uniform
        const int q4    = pbase >> 2;                        // uint4 index
        unsigned m[4] = {0u, 0u, 0u, 0u};
#pragma unroll
        for (int g4 = 0; g4 < 4; ++g4) {
#pragma unroll
            for (int w = 0; w < 4; ++w) {
                const int u4 = q4 + w * 4 + g4;   // uniform -> s_load
                const uint4 X = px4[u4];
                const uint4 Y = py4[u4];
                const uint4 Z = pz4[u4];
                bq_pair(X.x, Y.x, Z.x, qpx, qpy, qpz, nr2, m[w]);
                bq_pair(X.y, Y.y, Z.y, qpx, qpy, qpz, nr2, m[w]);
                bq_pair(X.z, Y.z, Z.z, qpx, qpy, qpz, nr2, m[w]);
                bq_pair(X.w, Y.w, Z.w, qpx, qpy, qpz, nr2, m[w]);
            }
        }
        // bit n of ev/od = pair (pbase+n) even/odd candidate
        unsigned long long ev =
              (unsigned long long)(m[0] & 0xFFFFu)
            | ((unsigned long long)(m[1] & 0xFFFFu) << 16)
            | ((unsigned long long)(m[2] & 0xFFFFu) << 32)
            | ((unsigned long long)(m[3] & 0xFFFFu) << 48);
        unsigned long long od =
              (unsigned long long)(m[0] >> 16)
            | ((unsigned long long)(m[1] >> 16) << 16)
            | ((unsigned long long)(m[2] >> 16) << 32)
            | ((unsigned long long)(m[3] >> 16) << 48);

        const int jb = 2 * pbase;
        while ((ev | od) && cnt < KNN) {
            const int pe = ev ? __builtin_ctzll(ev) : 127;
            const int po = od ? __builtin_ctzll(od) : 127;
            int j;
            if (pe <= po) { j = jb + 2 * pe;     ev &= ev - 1; }
            else          { j = jb + 2 * po + 1; od &= od - 1; }
            s_idx[q][cU * KNN + cnt] = (unsigned short)j;
            ++cnt;
        }
    }
    s_cnt[q][cU] = (unsigned char)cnt;
    __syncthreads();

    // ---- merge (wave 0, lane = query): first <=16 over this slice ----
    if (cU == 0) {
        const int qid = g * QPB + q;   // 0..16383
        unsigned short* __restrict__ rp =
            wsIdx + ((size_t)s * NBQ + qid) * KNN;
        int outc = 0;
        for (int c2 = 0; c2 < WAVES && outc < KNN; ++c2) {
            const int f = s_cnt[q][c2];
            const int take = f < (KNN - outc) ? f : (KNN - outc);
            for (int t = 0; t < take; ++t)
                rp[outc++] = s_idx[q][c2 * KNN + t];
        }
        wsCnt[qid * 4 + s] = (unsigned char)outc;
    }
}

__global__ __launch_bounds__(256)
void ballq_loss(const float* __restrict__ flow,
                const unsigned short* __restrict__ wsIdx,
                const unsigned char* __restrict__ wsCnt,
                float* __restrict__ partial)
{
    const int tid = blockIdx.x * 256 + threadIdx.x;
    const int qid = tid >> 4;          // one query per 16 lanes
    const int t   = tid & 15;          // k-slot
    const int b   = qid >> 13;
    const int iq  = qid & (NQ - 1);
    const float* __restrict__ flb = flow + (size_t)b * NQ * 3;

    const unsigned cw = *(const unsigned*)(wsCnt + qid * 4);
    const int b0 = cw & 0xFF;
    const int b1 = (cw >> 8)  & 0xFF;
    const int b2 = (cw >> 16) & 0xFF;
    const int c1 = b0, c2c = b0 + b1, c3 = b0 + b1 + b2;
    int tot = c3 + ((cw >> 24) & 0xFF);
    if (tot > KNN) tot = KNN;
    // tot >= 1 always: self is in-ball (exact f16 zero distance)

    const int seff = (t < tot) ? t : 0;   // padded slots -> first neighbor
    const int sl   = (seff >= c1) + (seff >= c2c) + (seff >= c3);
    const int cum  = (sl == 0) ? 0 : (sl == 1) ? c1 : (sl == 2) ? c2c : c3;
    const int j    = wsIdx[((size_t)sl * NBQ + qid) * KNN + (seff - cum)];

    const float fx = flb[iq * 3 + 0];
    const float fy = flb[iq * 3 + 1];
    const float fz = flb[iq * 3 + 2];
    float l = fabsf(fx - flb[j * 3 + 0]) +
              fabsf(fy - flb[j * 3 + 1]) +
              fabsf(fz - flb[j * 3 + 2]);

    for (int o = 32; o > 0; o >>= 1)
        l += __shfl_down(l, o, 64);
    __shared__ float sred[4];
    if ((threadIdx.x & 63) == 0) sred[threadIdx.x >> 6] = l;
    __syncthreads();
    if (threadIdx.x == 0)
        partial[blockIdx.x] = sred[0] + sred[1] + sred[2] + sred[3];
}

__global__ __launch_bounds__(1024)
void ballq_final(const float* __restrict__ partial, float* __restrict__ out)
{
    const int tid = threadIdx.x;       // 1024 threads, 16 waves
    float v = partial[tid];
    for (int o = 32; o > 0; o >>= 1)
        v += __shfl_down(v, o, 64);
    __shared__ float s[16];
    if ((tid & 63) == 0) s[tid >> 6] = v;
    __syncthreads();
    if (tid == 0) {
        float t = 0.0f;
#pragma unroll
        for (int w = 0; w < 16; ++w) t += s[w];
        out[0] = t * (1.0f / ((float)NB * NQ * KNN));
    }
}

extern "C" void kernel_launch(void* const* d_in, const int* in_sizes, int n_in,
                              void* d_out, int out_size, void* d_ws, size_t ws_size,
                              hipStream_t stream)
{
    (void)in_sizes; (void)n_in; (void)out_size; (void)ws_size;
    const float* pc   = (const float*)d_in[0];
    const float* flow = (const float*)d_in[1];
    float* out = (float*)d_out;

    // ws layout: packed planes (96 KB) | idx lists (2 MB) | counts (64 KB)
    //            | partials (4 KB)  -> ~2.26 MB total
    unsigned*       wsPk  = (unsigned*)d_ws;
    unsigned short* wsIdx = (unsigned short*)((char*)d_ws + (size_t)NB * 3 * NPAIRS * 4);
    unsigned char*  wsCnt = (unsigned char*)wsIdx + (size_t)SLICES * NBQ * KNN * 2;
    float* partial = (float*)(wsCnt + (size_t)NBQ * 4);

    ballq_prep<<<NB * NPAIRS / 256, 256, 0, stream>>>(pc, wsPk);
    ballq_scan<<<GROUPS * SLICES, THREADS, 0, stream>>>(pc, wsPk, wsIdx, wsCnt);
    ballq_loss<<<NBQ * 16 / 256, 256, 0, stream>>>(flow, wsIdx, wsCnt, partial);
    ballq_final<<<1, 1024, 0, stream>>>(partial, out);
}

// Round 16
// 33.472 us; speedup vs baseline: 1.8171x; 1.2239x over previous
//
#include <hip/hip_runtime.h>
#include <hip/hip_fp16.h>

// BallQLoss: B=2, N=8192, K=16, radius=0.5, L1 norm, mean over (B,N,K).
// v10: v7 structure (3 kernels, plain stores, NO single-address atomics)
// with gram-form eval: 6 VALU/pair (was 9). Staging computes a 4th LDS
// plane cn = (R^2-|p|^2)/2 packed f16x2; in-ball <=> w = q.p + cn - q2 > 0
// (q2 = |q|^2/2 per lane). Miss bits (sign of w) merged via lshr+and_or;
// per-round 4 NOTs recover hit masks; all-miss rounds skipped.
// K1 scan: 1024 blocks = 256 query-groups x 4 j-slices, 8 waves, ~33 KB
// LDS -> 4 blocks/CU = 8 waves/SIMD. Extraction in ascending j (pointnet2
// first-K semantics). Per-slice first-16 lists (u16) + count bytes -> d_ws.
// K2 loss: 16 lanes/query, slice-decode, padded slots -> first neighbor;
// tot==0 guard -> self (exact ref semantics, no poison index).
// K3 final: 1 block reduces 1024 partials -> mean. Replay-safe.

#define NQ   8192
#define NB   2
#define KNN  16
#define QPB  64
#define WAVES 8
#define THREADS (QPB * WAVES)          // 512
#define NBQ (NB * NQ)                  // 16384
#define GROUPS (NBQ / QPB)             // 256
#define SLICES 4
#define SL_PAIRS 1024                  // pairs per slice (2048 candidates)
#define WPP 128                        // pairs per wave (2 rounds of 64)
#define IDXROW 130                     // u16/row: 8 lists * 16 + 2 pad

static __device__ __forceinline__ unsigned pkrtz_u(float a, float b) {
    return __builtin_bit_cast(unsigned, __builtin_amdgcn_cvt_pkrtz(a, b));
}
static __device__ __forceinline__ __half2 u_as_h2(unsigned u) {
    return __builtin_bit_cast(__half2, u);
}
// one candidate PAIR, gram form: w = q.p + cn - q2 (packed f16).
// hit <=> w > 0; MISS bit = sign bit, merged into chain mm.
static __device__ __forceinline__ void bq_pair(unsigned xu, unsigned yu,
                                               unsigned zu, unsigned cu,
                                               __half2 qpx, __half2 qpy,
                                               __half2 qpz, __half2 q2p,
                                               unsigned& mm) {
    __half2 acc = __hsub2(u_as_h2(cu), q2p);          // cn - q2
    acc = __hfma2(u_as_h2(xu), qpx, acc);
    acc = __hfma2(u_as_h2(yu), qpy, acc);
    acc = __hfma2(u_as_h2(zu), qpz, acc);             // w
    mm = (__builtin_bit_cast(unsigned, acc) & 0x80008000u) | (mm >> 1);
}

__global__ __launch_bounds__(THREADS, 8)
void ballq_scan(const float* __restrict__ pc,
                unsigned short* __restrict__ wsIdx,
                unsigned char* __restrict__ wsCnt)
{
    __shared__ __align__(16) unsigned lx[SL_PAIRS];   // 4 KB each
    __shared__ __align__(16) unsigned ly[SL_PAIRS];
    __shared__ __align__(16) unsigned lz[SL_PAIRS];
    __shared__ __align__(16) unsigned lc[SL_PAIRS];   // cn plane
    __shared__ unsigned short s_idx[QPB][IDXROW];     // 16.6 KB
    __shared__ unsigned char  s_cnt[QPB][12];

    const int tid = threadIdx.x;
    const int q   = tid & 63;          // lane = query slot
    const int c   = tid >> 6;          // wave id
    const int s   = blockIdx.x & 3;    // j slice
    const int g   = blockIdx.x >> 2;   // query group 0..255
    const int b   = g >> 7;
    const int i   = (g & 127) * QPB + q;

    const float* __restrict__ pcb = pc + (size_t)b * NQ * 3;
    const float2* __restrict__ f2 = (const float2*)pcb;

    // ---- stage slice pairs + cn plane into LDS (f16x2) ----
    for (int p = tid; p < SL_PAIRS; p += THREADS) {
        const int gp = s * SL_PAIRS + p;
        const float2 v0 = f2[3 * gp + 0];   // (x_e, y_e)
        const float2 v1 = f2[3 * gp + 1];   // (z_e, x_o)
        const float2 v2 = f2[3 * gp + 2];   // (y_o, z_o)
        lx[p] = pkrtz_u(v0.x, v1.y);
        ly[p] = pkrtz_u(v0.y, v2.x);
        lz[p] = pkrtz_u(v1.x, v2.y);
        const float ne = v0.x * v0.x + v0.y * v0.y + v1.x * v1.x;
        const float no = v1.y * v1.y + v2.x * v2.x + v2.y * v2.y;
        lc[p] = pkrtz_u(0.125f - 0.5f * ne, 0.125f - 0.5f * no);
    }

    const float qx = pcb[i * 3 + 0];
    const float qy = pcb[i * 3 + 1];
    const float qz = pcb[i * 3 + 2];
    const __half2 qpx = u_as_h2(pkrtz_u(qx, qx));
    const __half2 qpy = u_as_h2(pkrtz_u(qy, qy));
    const __half2 qpz = u_as_h2(pkrtz_u(qz, qz));
    const float q2 = 0.5f * (qx * qx + qy * qy + qz * qz);
    const __half2 q2p = u_as_h2(pkrtz_u(q2, q2));

    __syncthreads();

    // ---- scan: wave c owns pairs [c*WPP, c*WPP+WPP), 2 rounds of 64 ----
    int cnt = 0;
    for (int r = 0; r < WPP / 64 && cnt < KNN; ++r) {
        const int pbase = c * WPP + r * 64;
        unsigned m[4] = {0u, 0u, 0u, 0u};   // MISS bit chains
#pragma unroll
        for (int g4 = 0; g4 < 4; ++g4) {
#pragma unroll
            for (int w = 0; w < 4; ++w) {
                const int pb = pbase + w * 16 + g4 * 4;
                const uint4 X = *(const uint4*)&lx[pb];  // broadcast b128
                const uint4 Y = *(const uint4*)&ly[pb];
                const uint4 Z = *(const uint4*)&lz[pb];
                const uint4 C = *(const uint4*)&lc[pb];
                bq_pair(X.x, Y.x, Z.x, C.x, qpx, qpy, qpz, q2p, m[w]);
                bq_pair(X.y, Y.y, Z.y, C.y, qpx, qpy, qpz, q2p, m[w]);
                bq_pair(X.z, Y.z, Z.z, C.z, qpx, qpy, qpz, q2p, m[w]);
                bq_pair(X.w, Y.w, Z.w, C.w, qpx, qpy, qpz, q2p, m[w]);
            }
        }
        // all-miss fast path
        if ((m[0] & m[1] & m[2] & m[3]) == 0xFFFFFFFFu) continue;
        const unsigned h0 = ~m[0], h1 = ~m[1], h2m = ~m[2], h3 = ~m[3];

        // bit n of ev/od = pair (pbase+n) even/odd candidate (hit bits)
        unsigned long long ev =
              (unsigned long long)(h0 & 0xFFFFu)
            | ((unsigned long long)(h1 & 0xFFFFu) << 16)
            | ((unsigned long long)(h2m & 0xFFFFu) << 32)
            | ((unsigned long long)(h3 & 0xFFFFu) << 48);
        unsigned long long od =
              (unsigned long long)(h0 >> 16)
            | ((unsigned long long)(h1 >> 16) << 16)
            | ((unsigned long long)(h2m >> 16) << 32)
            | ((unsigned long long)(h3 >> 16) << 48);

        const int jb = s * (2 * SL_PAIRS) + 2 * pbase;
        while ((ev | od) && cnt < KNN) {
            const int pe = ev ? __builtin_ctzll(ev) : 127;
            const int po = od ? __builtin_ctzll(od) : 127;
            int j;
            if (pe <= po) { j = jb + 2 * pe;     ev &= ev - 1; }
            else          { j = jb + 2 * po + 1; od &= od - 1; }
            s_idx[q][c * KNN + cnt] = (unsigned short)j;
            ++cnt;
        }
    }
    s_cnt[q][c] = (unsigned char)cnt;
    __syncthreads();

    // ---- merge (wave 0, lane = query): first <=16 over this slice ----
    if (c == 0) {
        const int qid = g * QPB + q;   // 0..16383
        unsigned short* __restrict__ rp =
            wsIdx + ((size_t)s * NBQ + qid) * KNN;
        int outc = 0;
        for (int c2 = 0; c2 < WAVES && outc < KNN; ++c2) {
            const int f = s_cnt[q][c2];
            const int take = f < (KNN - outc) ? f : (KNN - outc);
            for (int t = 0; t < take; ++t)
                rp[outc++] = s_idx[q][c2 * KNN + t];
        }
        wsCnt[qid * 4 + s] = (unsigned char)outc;
    }
}

__global__ __launch_bounds__(256)
void ballq_loss(const float* __restrict__ flow,
                const unsigned short* __restrict__ wsIdx,
                const unsigned char* __restrict__ wsCnt,
                float* __restrict__ partial)
{
    const int tid = blockIdx.x * 256 + threadIdx.x;
    const int qid = tid >> 4;          // one query per 16 lanes
    const int t   = tid & 15;          // k-slot
    const int b   = qid >> 13;
    const int iq  = qid & (NQ - 1);
    const float* __restrict__ flb = flow + (size_t)b * NQ * 3;

    const unsigned cw = *(const unsigned*)(wsCnt + qid * 4);
    const int b0 = cw & 0xFF;
    const int b1 = (cw >> 8)  & 0xFF;
    const int b2 = (cw >> 16) & 0xFF;
    const int c1 = b0, c2c = b0 + b1, c3 = b0 + b1 + b2;
    int tot = c3 + ((cw >> 24) & 0xFF);
    if (tot > KNN) tot = KNN;

    const int seff = (t < tot) ? t : 0;   // padded slots -> first neighbor
    const int sl   = (seff >= c1) + (seff >= c2c) + (seff >= c3);
    const int cum  = (sl == 0) ? 0 : (sl == 1) ? c1 : (sl == 2) ? c2c : c3;
    int j = wsIdx[((size_t)sl * NBQ + qid) * KNN + (seff - cum)];
    if (tot == 0) j = iq;   // pathological guard: self (diff = 0, = reference)

    const float fx = flb[iq * 3 + 0];
    const float fy = flb[iq * 3 + 1];
    const float fz = flb[iq * 3 + 2];
    float l = fabsf(fx - flb[j * 3 + 0]) +
              fabsf(fy - flb[j * 3 + 1]) +
              fabsf(fz - flb[j * 3 + 2]);

    for (int o = 32; o > 0; o >>= 1)
        l += __shfl_down(l, o, 64);
    __shared__ float sred[4];
    if ((threadIdx.x & 63) == 0) sred[threadIdx.x >> 6] = l;
    __syncthreads();
    if (threadIdx.x == 0)
        partial[blockIdx.x] = sred[0] + sred[1] + sred[2] + sred[3];
}

__global__ __launch_bounds__(1024)
void ballq_final(const float* __restrict__ partial, float* __restrict__ out)
{
    const int tid = threadIdx.x;       // 1024 threads, 16 waves
    float v = partial[tid];
    for (int o = 32; o > 0; o >>= 1)
        v += __shfl_down(v, o, 64);
    __shared__ float s[16];
    if ((tid & 63) == 0) s[tid >> 6] = v;
    __syncthreads();
    if (tid == 0) {
        float t = 0.0f;
#pragma unroll
        for (int w = 0; w < 16; ++w) t += s[w];
        out[0] = t * (1.0f / ((float)NB * NQ * KNN));
    }
}

extern "C" void kernel_launch(void* const* d_in, const int* in_sizes, int n_in,
                              void* d_out, int out_size, void* d_ws, size_t ws_size,
                              hipStream_t stream)
{
    (void)in_sizes; (void)n_in; (void)out_size; (void)ws_size;
    const float* pc   = (const float*)d_in[0];
    const float* flow = (const float*)d_in[1];
    float* out = (float*)d_out;

    // ws layout: idx lists (4 slices x 16384 q x 16 u16 = 2 MB),
    //            counts (16384 x 4 B), partials (1024 f32)
    unsigned short* wsIdx = (unsigned short*)d_ws;
    unsigned char*  wsCnt = (unsigned char*)d_ws + (size_t)SLICES * NBQ * KNN * 2;
    float* partial = (float*)(wsCnt + (size_t)NBQ * 4);

    ballq_scan<<<GROUPS * SLICES, THREADS, 0, stream>>>(pc, wsIdx, wsCnt);
    ballq_loss<<<NBQ * 16 / 256, 256, 0, stream>>>(flow, wsIdx, wsCnt, partial);
    ballq_final<<<1, 1024, 0, stream>>>(partial, out);
}